// Round 1
// baseline (853.610 us; speedup 1.0000x reference)
//
#include <hip/hip_runtime.h>

#define NEDGES 20000
#define KMAX 16
#define NTRIP (NEDGES*KMAX)
#define EMB 128
#define INTERM 64
#define NSPH 7
#define UNITS 128

#define ETILE 32
#define IB 4                       // interm values per chunk
#define NCHUNK (INTERM/IB)         // 16
#define KSL_PER_CHUNK (IB*EMB/32)  // 16 MFMA k-steps (K=32) per chunk

typedef __attribute__((ext_vector_type(8))) short short8;
typedef __attribute__((ext_vector_type(4))) float floatx4;

// pack two fp32 -> one uint holding two RNE-rounded bf16 (lo = a, hi = b)
__device__ __forceinline__ unsigned bf16pair(float a, float b) {
    unsigned ua = __float_as_uint(a), ub = __float_as_uint(b);
    ua = (ua + 0x7fffu + ((ua >> 16) & 1u)) >> 16;
    ub = (ub + 0x7fffu + ((ub >> 16) & 1u)) & 0xffff0000u;
    return ua | ub;
}

// inv[e*KMAX + k] = triplet index t (or -1 if absent; harness memsets to 0xFF first)
__global__ void scatter_inv(const int* __restrict__ idr, const int* __restrict__ kix,
                            int* __restrict__ inv) {
    int t = blockIdx.x * 256 + threadIdx.x;
    if (t < NTRIP) {
        int e = idr[t], k = kix[t];
        if ((unsigned)e < NEDGES && (unsigned)k < KMAX)
            inv[e * KMAX + k] = t;
    }
}

// W2f: weight (emb, interm, o) fp32 -> bf16 in MFMA B-fragment order.
// Flat uint4 index = (nt*256 + ks)*64 + lane; element j: k = ks*32 + (lane>>4)*8 + j,
// o = nt*16 + (lane&15); k = i*128 + emb.
__global__ void build_w2f(const float* __restrict__ w, uint4* __restrict__ w2f) {
    int idx  = blockIdx.x * 256 + threadIdx.x;    // 0 .. 131071
    int lane = idx & 63;
    int ks   = (idx >> 6) & 255;
    int nt   = idx >> 14;
    int o  = nt * 16 + (lane & 15);
    int kb = ks * 32 + (lane >> 4) * 8;
    unsigned pk[4];
#pragma unroll
    for (int jj = 0; jj < 4; ++jj) {
        int k0 = kb + 2 * jj;
        int i0 = k0 >> 7, e0 = k0 & 127;
        int i1 = (k0 + 1) >> 7, e1 = (k0 + 1) & 127;
        float f0 = w[((size_t)e0 * INTERM + i0) * UNITS + o];
        float f1 = w[((size_t)e1 * INTERM + i1) * UNITS + o];
        pk[jj] = bf16pair(f0, f1);
    }
    w2f[idx] = make_uint4(pk[0], pk[1], pk[2], pk[3]);
}

__global__ __launch_bounds__(256, 2)
void eib_main(const float* __restrict__ rbf, const float* __restrict__ sph,
              const float* __restrict__ m, const int* __restrict__ inv,
              const uint4* __restrict__ w2f, float* __restrict__ out) {
    __shared__ float sph_s[ETILE * NSPH * KMAX];  // 14336 B
    __shared__ uint4 a_s[2 * 16 * 64];            // 32768 B, A-fragment order

    const int tid = threadIdx.x;
    const int e0  = blockIdx.x * ETILE;

    // stage sph tile (coalesced)
    for (int idx = tid; idx < ETILE * NSPH * KMAX; idx += 256)
        sph_s[idx] = sph[(size_t)e0 * NSPH * KMAX + idx];
    __syncthreads();

    // ---- phase 1: sum_k[s][q] for (edge le, emb range p*16..p*16+15), in registers
    const int le = tid >> 3;   // 0..31 edge within tile
    const int p  = tid & 7;    // emb 16-group

    float sk[NSPH][16];
#pragma unroll
    for (int s = 0; s < NSPH; ++s)
#pragma unroll
        for (int q = 0; q < 16; ++q) sk[s][q] = 0.f;

    int tix[KMAX];
    {
        const int4* ip = (const int4*)(inv + (size_t)(e0 + le) * KMAX);
#pragma unroll
        for (int g = 0; g < 4; ++g) {
            int4 v = ip[g];
            tix[4*g+0] = v.x; tix[4*g+1] = v.y; tix[4*g+2] = v.z; tix[4*g+3] = v.w;
        }
    }

#pragma unroll 2
    for (int k = 0; k < KMAX; ++k) {
        int t = tix[k];
        if (t >= 0) {
            const float4* mp = (const float4*)(m + (size_t)t * EMB + p * 16);
            float4 a = mp[0], b = mp[1], c = mp[2], d = mp[3];
            float mv[16] = {a.x,a.y,a.z,a.w, b.x,b.y,b.z,b.w,
                            c.x,c.y,c.z,c.w, d.x,d.y,d.z,d.w};
#pragma unroll
            for (int s = 0; s < NSPH; ++s) {
                float cs = sph_s[(le * NSPH + s) * KMAX + k];
#pragma unroll
                for (int q = 0; q < 16; ++q)
                    sk[s][q] = fmaf(cs, mv[q], sk[s][q]);
            }
        }
    }

    // ---- phases 2a/2b per interm-chunk
    const int lane = tid & 63;
    const int wid  = tid >> 6;
    const int wm = wid & 1;    // which 16-edge M-tile
    const int wn = wid >> 1;   // which 64-col N-half
    const int em = le & 15, mt = le >> 4;

    floatx4 acc[4] = {{0,0,0,0},{0,0,0,0},{0,0,0,0},{0,0,0,0}};

    for (int ch = 0; ch < NCHUNK; ++ch) {
        const int i0 = ch * IB;
        __syncthreads();   // prev chunk's MFMA reads of a_s complete

        // 2a: A-chunk = rbf . sum_k, bf16, written in A-fragment order
#pragma unroll
        for (int il = 0; il < IB; ++il) {
            float rv[NSPH];
            const float* rp = rbf + ((size_t)(e0 + le) * INTERM + (i0 + il)) * NSPH;
#pragma unroll
            for (int s = 0; s < NSPH; ++s) rv[s] = rp[s];
#pragma unroll
            for (int h = 0; h < 2; ++h) {          // two emb-octets of this thread
                unsigned pk[4];
#pragma unroll
                for (int jj = 0; jj < 4; ++jj) {
                    int q0 = h * 8 + 2 * jj;
                    float v0 = 0.f, v1 = 0.f;
#pragma unroll
                    for (int s = 0; s < NSPH; ++s) {
                        v0 = fmaf(rv[s], sk[s][q0],     v0);
                        v1 = fmaf(rv[s], sk[s][q0 + 1], v1);
                    }
                    pk[jj] = bf16pair(v0, v1);
                }
                int eo   = p * 2 + h;              // emb-octet index 0..15
                int ksl  = il * 4 + (eo >> 2);     // k-step within chunk
                int slot = (eo & 3) * 16 + em;     // lane slot in fragment
                a_s[(mt * 16 + ksl) * 64 + slot] = make_uint4(pk[0], pk[1], pk[2], pk[3]);
            }
        }
        __syncthreads();

        // 2b: MFMA. wave (wm,wn): edges [16wm,16wm+16) x outs [64wn,64wn+64)
#pragma unroll 4
        for (int ksl = 0; ksl < KSL_PER_CHUNK; ++ksl) {
            uint4 av = a_s[(wm * 16 + ksl) * 64 + lane];
            short8 af = __builtin_bit_cast(short8, av);
#pragma unroll
            for (int j = 0; j < 4; ++j) {
                int nt = wn * 4 + j;
                uint4 wv = w2f[((size_t)(nt * 256 + ch * 16 + ksl)) * 64 + lane];
                short8 bf = __builtin_bit_cast(short8, wv);
                acc[j] = __builtin_amdgcn_mfma_f32_16x16x32_bf16(af, bf, acc[j], 0, 0, 0);
            }
        }
    }

    // epilogue: C/D layout col=lane&15, row=(lane>>4)*4+reg
#pragma unroll
    for (int j = 0; j < 4; ++j) {
        int o = wn * 64 + j * 16 + (lane & 15);
#pragma unroll
        for (int r = 0; r < 4; ++r) {
            int mrow = (lane >> 4) * 4 + r;
            out[(size_t)(e0 + wm * 16 + mrow) * UNITS + o] = acc[j][r];
        }
    }
}

extern "C" void kernel_launch(void* const* d_in, const int* in_sizes, int n_in,
                              void* d_out, int out_size, void* d_ws, size_t ws_size,
                              hipStream_t stream) {
    const float* rbf = (const float*)d_in[0];
    const float* sph = (const float*)d_in[1];
    const float* m   = (const float*)d_in[2];
    const float* w   = (const float*)d_in[3];
    const int*   idr = (const int*)d_in[4];
    const int*   kix = (const int*)d_in[5];
    float* out = (float*)d_out;

    int*  inv = (int*)d_ws;
    size_t invBytes = (size_t)NEDGES * KMAX * sizeof(int);               // 1.28 MB
    uint4* w2f = (uint4*)((char*)d_ws + ((invBytes + 255) & ~(size_t)255)); // +2 MB

    hipMemsetAsync(inv, 0xFF, invBytes, stream);
    scatter_inv<<<(NTRIP + 255) / 256, 256, 0, stream>>>(idr, kix, inv);
    build_w2f<<<512, 256, 0, stream>>>(w, w2f);
    eib_main<<<NEDGES / ETILE, 256, 0, stream>>>(rbf, sph, m, inv, w2f, out);
}

// Round 2
// 498.944 us; speedup vs baseline: 1.7108x; 1.7108x over previous
//
#include <hip/hip_runtime.h>

#define NEDGES 20000
#define KMAX 16
#define NTRIP (NEDGES*KMAX)
#define EMB 128
#define INTERM 64
#define NSPH 7
#define UNITS 128
#define MT_TOTAL (NEDGES/16)    // 1250 M-tiles of 16 edges
#define KSTEPS 256              // K = 8192 / 32

typedef __attribute__((ext_vector_type(8))) short short8;
typedef __attribute__((ext_vector_type(4))) float floatx4;

// pack two fp32 -> one uint holding two RNE-rounded bf16 (lo = a, hi = b)
__device__ __forceinline__ unsigned bf16pair(float a, float b) {
    unsigned ua = __float_as_uint(a), ub = __float_as_uint(b);
    ua = (ua + 0x7fffu + ((ua >> 16) & 1u)) >> 16;
    ub = (ub + 0x7fffu + ((ub >> 16) & 1u)) & 0xffff0000u;
    return ua | ub;
}

// inv[e*KMAX + k] = triplet index t (or -1 if absent; memset 0xFF first)
__global__ void scatter_inv(const int* __restrict__ idr, const int* __restrict__ kix,
                            int* __restrict__ inv) {
    int t = blockIdx.x * 256 + threadIdx.x;
    if (t < NTRIP) {
        int e = idr[t], k = kix[t];
        if ((unsigned)e < NEDGES && (unsigned)k < KMAX)
            inv[e * KMAX + k] = t;
    }
}

// W2f: weight (emb, interm, o) fp32 -> bf16 in MFMA B-fragment order.
// uint4 index = (nt*256 + ks)*64 + lane; element j: k = ks*32 + (lane>>4)*8 + j,
// o = nt*16 + (lane&15); k-mapping: k = i*128 + emb.
__global__ void build_w2f(const float* __restrict__ w, uint4* __restrict__ w2f) {
    int idx  = blockIdx.x * 256 + threadIdx.x;    // 0 .. 131071
    int lane = idx & 63;
    int ks   = (idx >> 6) & 255;
    int nt   = idx >> 14;
    int o  = nt * 16 + (lane & 15);
    int kb = ks * 32 + (lane >> 4) * 8;
    unsigned pk[4];
#pragma unroll
    for (int jj = 0; jj < 4; ++jj) {
        int k0 = kb + 2 * jj;
        int i0 = k0 >> 7, e0 = k0 & 127;
        int i1 = (k0 + 1) >> 7, e1 = (k0 + 1) & 127;
        float f0 = w[((size_t)e0 * INTERM + i0) * UNITS + o];
        float f1 = w[((size_t)e1 * INTERM + i1) * UNITS + o];
        pk[jj] = bf16pair(f0, f1);
    }
    w2f[idx] = make_uint4(pk[0], pk[1], pk[2], pk[3]);
}

// build_a: one block per 16-edge M-tile. Computes sum_k = sph@m2 in registers,
// then A = rbf . sum_k as bf16, stored to ws in MFMA A-fragment order:
//   uint4 index = (mtLocal*256 + ks)*64 + lane,
//   element j: edge = mt*16 + (lane&15), k = ks*32 + (lane>>4)*8 + j.
__global__ __launch_bounds__(256)
void build_a(const float* __restrict__ rbf, const float* __restrict__ sph,
             const float* __restrict__ m, const int* __restrict__ inv,
             uint4* __restrict__ aw, int mt0) {
    __shared__ float sph_s[16 * 112];   // 7168 B
    __shared__ float rbf_s[16 * 520];   // 33280 B (rows of 8 per i, le-stride 520)

    const int tid = threadIdx.x;
    const int le = tid >> 4;            // edge within tile 0..15
    const int p  = tid & 15;            // emb octet 0..15 (embs p*8..p*8+7)
    const size_t e0 = (size_t)(mt0 + blockIdx.x) * 16;

    // stage sph tile (coalesced)
    for (int idx = tid; idx < 16 * 112; idx += 256)
        sph_s[idx] = sph[e0 * 112 + idx];
    // stage rbf tile, padded to 8 floats per i (thread (le,p) stages i = p+16*ii)
#pragma unroll
    for (int ii = 0; ii < 4; ++ii) {
        int i = p + ii * 16;
        const float* rp = rbf + (e0 + le) * 448 + (size_t)i * 7;
        float* dp = rbf_s + le * 520 + i * 8;
#pragma unroll
        for (int s = 0; s < NSPH; ++s) dp[s] = rp[s];
    }
    __syncthreads();

    // phase 1: sum_k[s][j] for (edge le, embs p*8+j)
    float sk[NSPH][8];
#pragma unroll
    for (int s = 0; s < NSPH; ++s)
#pragma unroll
        for (int q = 0; q < 8; ++q) sk[s][q] = 0.f;

    const int4* ip = (const int4*)(inv + (e0 + le) * KMAX);
#pragma unroll
    for (int g = 0; g < 4; ++g) {
        int4 v = ip[g];
        int ts[4] = {v.x, v.y, v.z, v.w};
#pragma unroll
        for (int kk = 0; kk < 4; ++kk) {
            int t = ts[kk];
            int k = g * 4 + kk;
            if (t >= 0) {
                const float4* mp = (const float4*)(m + (size_t)t * EMB + p * 8);
                float4 a = mp[0], b = mp[1];
                float mv[8] = {a.x, a.y, a.z, a.w, b.x, b.y, b.z, b.w};
#pragma unroll
                for (int s = 0; s < NSPH; ++s) {
                    float cs = sph_s[le * 112 + s * 16 + k];
#pragma unroll
                    for (int q = 0; q < 8; ++q)
                        sk[s][q] = fmaf(cs, mv[q], sk[s][q]);
                }
            }
        }
    }

    // phase 2: A[le][i][p*8+j] = sum_s rbf[le][i][s]*sk[s][j]; write frag-order bf16
    const size_t obase = (size_t)blockIdx.x * 256;
    const int slot = (p & 3) * 16 + le;   // lane within fragment
#pragma unroll 4
    for (int i = 0; i < INTERM; ++i) {
        const float4 ra = *(const float4*)(rbf_s + le * 520 + i * 8);
        const float4 rb = *(const float4*)(rbf_s + le * 520 + i * 8 + 4);
        float rv[NSPH] = {ra.x, ra.y, ra.z, ra.w, rb.x, rb.y, rb.z};
        unsigned pk[4];
#pragma unroll
        for (int jj = 0; jj < 4; ++jj) {
            float v0 = 0.f, v1 = 0.f;
#pragma unroll
            for (int s = 0; s < NSPH; ++s) {
                v0 = fmaf(rv[s], sk[s][2 * jj], v0);
                v1 = fmaf(rv[s], sk[s][2 * jj + 1], v1);
            }
            pk[jj] = bf16pair(v0, v1);
        }
        aw[(obase + (size_t)(i * 4 + (p >> 2))) * 64 + slot] =
            make_uint4(pk[0], pk[1], pk[2], pk[3]);
    }
}

// gemm: one block per 2 M-tiles (32 edges), full N=128. A-slab staged via LDS,
// w2f read once per block (L2-resident). Wave wid owns nt {2*wid, 2*wid+1}.
__global__ __launch_bounds__(256)
void gemm(const uint4* __restrict__ afrag, const uint4* __restrict__ w2f,
          float* __restrict__ out, int mt0) {
    __shared__ uint4 buf[2 * 16 * 64];  // 32 KB: [mtHalf][ksl 0..15][lane]

    const int tid = threadIdx.x;
    const int lane = tid & 63, wid = tid >> 6;
    const int lA = 2 * blockIdx.x;      // local m-tile pair base

    floatx4 acc[2][2] = {{{0,0,0,0},{0,0,0,0}},{{0,0,0,0},{0,0,0,0}}};

    const size_t srcA = (size_t)lA * KSTEPS * 64;       // uint4 index
    const size_t srcB = (size_t)(lA + 1) * KSTEPS * 64;

    for (int sl = 0; sl < 16; ++sl) {   // 16 slabs x 16 k-steps
        // stage 2048 uint4 (32 KB), coalesced: flat f = j*256 + tid
#pragma unroll
        for (int j = 0; j < 8; ++j) {
            int f = j * 256 + tid;             // 0..2047
            int half = f >> 10;                // which m-tile
            int w    = f & 1023;               // ksl*64 + lane
            size_t src = (half ? srcB : srcA) + (size_t)(sl * 16) * 64 + w;
            buf[f] = afrag[src];
        }
        __syncthreads();

        const int ksg = sl * 16;
#pragma unroll
        for (int ksl = 0; ksl < 16; ++ksl) {
            uint4 a0 = buf[ksl * 64 + lane];
            uint4 a1 = buf[(16 + ksl) * 64 + lane];
            short8 af0 = __builtin_bit_cast(short8, a0);
            short8 af1 = __builtin_bit_cast(short8, a1);
#pragma unroll
            for (int q = 0; q < 2; ++q) {
                int nt = 2 * wid + q;
                uint4 wv = w2f[((size_t)nt * KSTEPS + ksg + ksl) * 64 + lane];
                short8 bf = __builtin_bit_cast(short8, wv);
                acc[0][q] = __builtin_amdgcn_mfma_f32_16x16x32_bf16(af0, bf, acc[0][q], 0, 0, 0);
                acc[1][q] = __builtin_amdgcn_mfma_f32_16x16x32_bf16(af1, bf, acc[1][q], 0, 0, 0);
            }
        }
        __syncthreads();
    }

    // epilogue: C/D layout col=lane&15 (n), row=(lane>>4)*4+reg (m)
    const int col = lane & 15, rbase = (lane >> 4) * 4;
#pragma unroll
    for (int h = 0; h < 2; ++h) {
        size_t ebase = (size_t)(mt0 + lA + h) * 16;
#pragma unroll
        for (int q = 0; q < 2; ++q) {
            int o = (2 * wid + q) * 16 + col;
#pragma unroll
            for (int r = 0; r < 4; ++r)
                out[(ebase + rbase + r) * UNITS + o] = acc[h][q][r];
        }
    }
}

extern "C" void kernel_launch(void* const* d_in, const int* in_sizes, int n_in,
                              void* d_out, int out_size, void* d_ws, size_t ws_size,
                              hipStream_t stream) {
    const float* rbf = (const float*)d_in[0];
    const float* sph = (const float*)d_in[1];
    const float* m   = (const float*)d_in[2];
    const float* w   = (const float*)d_in[3];
    const int*   idr = (const int*)d_in[4];
    const int*   kix = (const int*)d_in[5];
    float* out = (float*)d_out;

    // ws layout: inv (1.28 MB, pad to 0x140000) | w2f (2 MB) | A (group x 256 KB)
    int*   inv = (int*)d_ws;
    uint4* w2f = (uint4*)((char*)d_ws + 0x140000);
    uint4* A   = (uint4*)((char*)d_ws + 0x340000);
    const size_t fixedBytes = 0x340000;
    const size_t perMT = (size_t)KSTEPS * 64 * 16;   // 262144 B per M-tile

    size_t avail = (ws_size > fixedBytes) ? ws_size - fixedBytes : 0;
    long G = (long)(avail / perMT);
    if (G > MT_TOTAL) G = MT_TOTAL;
    if (G >= 2) G &= ~1L;
    if (G < 2) G = 2;   // ws_size >= 3.9 MB required (round-1 used 3.4 MB fine)

    hipMemsetAsync(inv, 0xFF, (size_t)NEDGES * KMAX * sizeof(int), stream);
    scatter_inv<<<(NTRIP + 255) / 256, 256, 0, stream>>>(idr, kix, inv);
    build_w2f<<<512, 256, 0, stream>>>(w, w2f);

    for (long done = 0; done < MT_TOTAL; done += G) {
        long g = MT_TOTAL - done; if (g > G) g = G;
        build_a<<<(int)g, 256, 0, stream>>>(rbf, sph, m, inv, A, (int)done);
        gemm<<<(int)(g / 2), 256, 0, stream>>>(A, w2f, out, (int)done);
    }
}